// Round 21
// baseline (132.709 us; speedup 1.0000x reference)
//
#include <hip/hip_runtime.h>
#include <stdint.h>

#define HD 128
#define BSH 8        // bucket = 256 dst nodes
#define BNODES 256
#define PER 8        // nodes per wave in k_aggh
#define SCAP 256     // staged edge capacity per wave
#define BINBLK 256   // binning grid

typedef float f32x4 __attribute__((ext_vector_type(4)));
typedef short s16x8 __attribute__((ext_vector_type(8)));

static inline int idiv(int a, int b) { return (a + b - 1) / b; }

__device__ __forceinline__ unsigned short f2b(float f) {
  unsigned u = __float_as_uint(f);
  return (unsigned short)((u + 0x7fffu + ((u >> 16) & 1u)) >> 16);
}

// ---------------- fused: W2 frag transform (blocks 0..7) + bucket histogram (8..) ----
__global__ void __launch_bounds__(256) k_w2t_bincount(
    const float* __restrict__ W2, unsigned* __restrict__ w2f,
    float4* __restrict__ td, const int* __restrict__ edst,
    int* __restrict__ cntm, int E, int NB, int chunk, int N) {
  if (blockIdx.x < 8) {
    int f = blockIdx.x * 256 + threadIdx.x;
    if (f == 0) td[N] = make_float4(0.f, 0.f, 0.f, 0.f);  // sentinel row
    if (f >= 2048) return;
    int c = f >> 8, s = (f >> 6) & 3, lane = f & 63;
    int col = c * 16 + (lane & 15);
    int kb = s * 32 + (lane >> 4) * 8;
    unsigned hi4[4], lo4[4];
#pragma unroll
    for (int j = 0; j < 4; ++j) {
      float w0 = W2[(kb + 2 * j) * HD + col];
      float w1 = W2[(kb + 2 * j + 1) * HD + col];
      unsigned short h0 = f2b(w0), h1 = f2b(w1);
      float r0 = w0 - __uint_as_float((unsigned)h0 << 16);
      float r1 = w1 - __uint_as_float((unsigned)h1 << 16);
      unsigned short l0 = f2b(r0), l1 = f2b(r1);
      hi4[j] = ((unsigned)h1 << 16) | h0;
      lo4[j] = ((unsigned)l1 << 16) | l0;
    }
    *(uint4*)&w2f[f * 4] = make_uint4(hi4[0], hi4[1], hi4[2], hi4[3]);
    *(uint4*)&w2f[8192 + f * 4] = make_uint4(lo4[0], lo4[1], lo4[2], lo4[3]);
    return;
  }
  __shared__ int hist[512];
  int blk = blockIdx.x - 8;
  for (int b = threadIdx.x; b < 512; b += 256) hist[b] = 0;
  __syncthreads();
  int s0 = blk * chunk, s1 = min(E, s0 + chunk);
  for (int k = s0 + threadIdx.x; k < s1; k += 256)
    atomicAdd(&hist[edst[k] >> BSH], 1);
  __syncthreads();
  for (int b = threadIdx.x; b < NB; b += 256)
    cntm[(size_t)b * BINBLK + blk] = hist[b];
}

// ---------------- exclusive scan over M elements (3 kernels, coalesced) ----------
__global__ void k_scan1(const int* __restrict__ cnt, int* __restrict__ part, int N) {
  __shared__ int sh[256];
  int t = threadIdx.x;
  int base = blockIdx.x * 1024 + t * 4;
  int s = 0;
#pragma unroll
  for (int u = 0; u < 4; ++u) { int idx = base + u; if (idx < N) s += cnt[idx]; }
  sh[t] = s; __syncthreads();
  for (int off = 128; off > 0; off >>= 1) { if (t < off) sh[t] += sh[t + off]; __syncthreads(); }
  if (t == 0) part[blockIdx.x] = sh[0];
}

__global__ void k_scan2(int* part, int nb) {
  __shared__ int sh[1024];
  int t = threadIdx.x;
  int v = (t < nb) ? part[t] : 0;
  sh[t] = v;
  __syncthreads();
  for (int off = 1; off < 1024; off <<= 1) {
    int add = (t >= off) ? sh[t - off] : 0;
    __syncthreads();
    sh[t] += add;
    __syncthreads();
  }
  if (t < nb) part[t] = sh[t] - v;
}

__global__ void k_scan3(const int* __restrict__ cnt, const int* __restrict__ part,
                        int* __restrict__ out, int N) {
  __shared__ int sa[256], sb[256];
  int t = threadIdx.x;
  int base = blockIdx.x * 1024 + t * 4;
  int v[4]; int s = 0;
#pragma unroll
  for (int u = 0; u < 4; ++u) { int idx = base + u; v[u] = (idx < N) ? cnt[idx] : 0; s += v[u]; }
  sa[t] = s; __syncthreads();
  int* cur = sa; int* nxt = sb;
  for (int off = 1; off < 256; off <<= 1) {
    int val = cur[t] + ((t >= off) ? cur[t - off] : 0);
    nxt[t] = val; __syncthreads();
    int* tmp = cur; cur = nxt; nxt = tmp;
  }
  int excl = cur[t] - s + part[blockIdx.x];
#pragma unroll
  for (int u = 0; u < 4; ++u) {
    int idx = base + u;
    if (idx < N) { out[idx] = excl; excl += v[u]; }
  }
}

// ---------------- pass 2: bin edges into bucket-grouped records ----------------
__global__ void __launch_bounds__(256) k_binscatter(const int* __restrict__ esrc,
                                                    const int* __restrict__ edst,
                                                    const int* __restrict__ scanM,
                                                    unsigned* __restrict__ recs,
                                                    int E, int NB, int chunk) {
  __shared__ int cur[512];
  int blk = blockIdx.x;
  for (int b = threadIdx.x; b < NB; b += 256) cur[b] = scanM[(size_t)b * BINBLK + blk];
  __syncthreads();
  int s0 = blk * chunk, s1 = min(E, s0 + chunk);
  for (int k = s0 + threadIdx.x; k < s1; k += 256) {
    int d = edst[k], s = esrc[k];
    int b = d >> BSH;
    int pos = atomicAdd(&cur[b], 1);
    recs[pos] = ((unsigned)(d & (BNODES - 1)) << 23) | (unsigned)s;
  }
}

// ---------------- pass 3: per-bucket counting sort -> quad-padded CSR + node prep ----
// Rows padded to multiples of 4 with sentinel edges (-> zero td row). Bucket b's
// padded rows live at base_p = rs + b*3*BNODES.
__global__ void __launch_bounds__(256) k_bucketsort(const unsigned* __restrict__ recs,
                                                    const int* __restrict__ scanM,
                                                    const float* __restrict__ x,
                                                    const int* __restrict__ bids,
                                                    unsigned* __restrict__ ssrc16,
                                                    int* __restrict__ row_start,
                                                    int* __restrict__ cnt,
                                                    float* __restrict__ dinv,
                                                    float2* __restrict__ xs,
                                                    int* __restrict__ gstart,
                                                    int NB, int N, int G, int E) {
  __shared__ int count[BNODES], excl[BNODES], cur[BNODES], psum[32];
  int b = blockIdx.x;
  int t = threadIdx.x;
  count[t] = 0;
  __syncthreads();
  int rs = scanM[(size_t)b * BINBLK];
  int re = (b == NB - 1) ? E : scanM[(size_t)(b + 1) * BINBLK];
  int base_p = rs + b * 3 * BNODES;
  for (int k = rs + t; k < re; k += 256) atomicAdd(&count[recs[k] >> 23], 1);
  __syncthreads();
  if (t < 32) {
    int s = 0;
#pragma unroll
    for (int u = 0; u < 8; ++u) s += (count[t * 8 + u] + 3) & ~3;
    psum[t] = s;
  }
  __syncthreads();
  if (t == 0) {
    int run = 0;
    for (int d = 0; d < 32; ++d) { int v = psum[d]; psum[d] = run; run += v; }
  }
  __syncthreads();
  if (t < 32) {
    int run = psum[t];
#pragma unroll
    for (int u = 0; u < 8; ++u) {
      excl[t * 8 + u] = run;
      run += (count[t * 8 + u] + 3) & ~3;
    }
  }
  __syncthreads();
  {
    int d = t;
    int i = b * BNODES + d;
    if (i < N) {
      cnt[i] = count[d];
      row_start[i] = base_p + excl[d];
      int pad = (count[d] + 3) & ~3;
      for (int pp = count[d]; pp < pad; ++pp)   // sentinel pad slots
        ssrc16[base_p + excl[d] + pp] = (unsigned)N << 4;
      float di = rsqrtf((float)(count[d] + 1));
      dinv[i] = di;
      float2 xv = *(const float2*)&x[2 * i];
      xs[i] = make_float2(di * xv.x, di * xv.y);
      int g = bids[i];
      if (i == 0)
        for (int gg = 0; gg <= g; ++gg) gstart[gg] = 0;
      int gn = (i == N - 1) ? G : bids[i + 1];
      for (int gg = g + 1; gg <= gn; ++gg) gstart[gg] = i + 1;
    }
    cur[d] = excl[d];
  }
  __syncthreads();
  for (int k = rs + t; k < re; k += 256) {
    unsigned r = recs[k];
    int dl = r >> 23;
    int pos = base_p + atomicAdd(&cur[dl], 1);
    ssrc16[pos] = (r & 0x007fffffu) << 4;   // byte offset into td (16B rows)
  }
}

// ---------------- layer-1 aggregation -> td = (t0, t1, dinv, 0) ----------------
__global__ void k_aggx2(const int* __restrict__ row_start, const int* __restrict__ cnt,
                        const unsigned* __restrict__ ssrc16, const float2* __restrict__ xs,
                        const float* __restrict__ dinv, float4* __restrict__ td, int N) {
  int i = blockIdx.x * 256 + threadIdx.x;
  if (i >= N) return;
  int rs = row_start[i], re = rs + cnt[i];
  float a0 = 0.f, a1 = 0.f, b0 = 0.f, b1 = 0.f;
  int k = rs;
  for (; k + 3 < re; k += 4) {
    unsigned v0 = ssrc16[k] >> 4, v1 = ssrc16[k + 1] >> 4;
    unsigned v2 = ssrc16[k + 2] >> 4, v3 = ssrc16[k + 3] >> 4;
    float2 p0 = xs[v0], p1 = xs[v1], p2 = xs[v2], p3 = xs[v3];
    a0 += p0.x + p1.x; a1 += p0.y + p1.y;
    b0 += p2.x + p3.x; b1 += p2.y + p3.y;
  }
  for (; k < re; ++k) {
    float2 p = xs[ssrc16[k] >> 4];
    a0 += p.x; a1 += p.y;
  }
  a0 += b0; a1 += b1;
  float2 self = xs[i];
  float di = dinv[i];
  td[i] = make_float4(di * (a0 + self.x), di * (a1 + self.y), di, 0.f);
}

// ---------------- fused layer-1 transform + layer-2 aggregation ----------------
// Wave = strip of PER nodes (quad-padded CSR within one bucket). Stage the strip
// (<=SCAP edges) into per-wave LDS with 4 64-wide gathers, then consume 4 edges
// per ds_read_b128: quarter-wave q = lane>>4 takes edge 4p+q; lane owns a
// feature OCTET (2 x f32x4). Node epilogue: shfl_xor(16,32) reduce; 16-lane
// uint4 coalesced store.
__global__ void __launch_bounds__(256) k_aggh(
    const int* __restrict__ row_start, const int* __restrict__ cnt,
    const unsigned* __restrict__ ssrc16, const float4* __restrict__ td,
    const float* __restrict__ W1, const float* __restrict__ b1,
    unsigned* __restrict__ m_b, int N) {
  __shared__ float4 sbuf[4][SCAP];   // 16 KiB, per-wave slabs
  int wave = threadIdx.x >> 6;
  int lane = threadIdx.x & 63;
  int wid = blockIdx.x * 4 + wave;
  int i0 = wid * PER;
  if (i0 >= N) return;
  int nn = min(N - i0, PER);
  int qg = lane >> 4;                 // quarter-wave id (edge slot)
  int sl = lane & 15;                 // sub-lane: feature octet owner
  int fb = sl * 8;                    // feature octet base
  f32x4 w0a = *(const f32x4*)&W1[fb],      w0b = *(const f32x4*)&W1[fb + 4];
  f32x4 w1a = *(const f32x4*)&W1[HD + fb], w1b = *(const f32x4*)&W1[HD + fb + 4];
  f32x4 bba = *(const f32x4*)&b1[fb],      bbb = *(const f32x4*)&b1[fb + 4];
  int mydeg = (lane < nn) ? cnt[i0 + lane] : 0;
  int myrow = (lane < nn) ? row_start[i0 + lane] : 0;
  float4 mytd = (lane < nn) ? td[i0 + lane] : make_float4(0.f, 0.f, 0.f, 0.f);
  int mx = __float_as_int(mytd.x), my = __float_as_int(mytd.y), mz = __float_as_int(mytd.z);
  int rs0 = __builtin_amdgcn_readfirstlane(myrow);
  int last = nn - 1;
  int rsEnd = __builtin_amdgcn_readlane(myrow, last) +
              ((__builtin_amdgcn_readlane(mydeg, last) + 3) & ~3);
  int total = rsEnd - rs0;            // multiple of 4; strip stays inside its bucket
  const char* tdc = (const char*)td;
  bool staged = (total <= SCAP);
  if (staged) {
#pragma unroll
    for (int w = 0; w < SCAP / 64; ++w) {
      int sl2 = w * 64 + lane;
      if (sl2 < total) {
        unsigned off = ssrc16[rs0 + sl2];
        sbuf[wave][sl2] = *(const float4*)(tdc + off);
      }
    }
  }
  int k = 0;
  const f32x4 zero4 = {0.f, 0.f, 0.f, 0.f};
#define EDGE_Q(T, A, B) { \
    f32x4 ha = f32x4{T.y, T.y, T.y, T.y} * w1a + bba; \
    f32x4 hb = f32x4{T.y, T.y, T.y, T.y} * w1b + bbb; \
    ha = f32x4{T.x, T.x, T.x, T.x} * w0a + ha; \
    hb = f32x4{T.x, T.x, T.x, T.x} * w0b + hb; \
    ha = __builtin_elementwise_max(ha, zero4); \
    hb = __builtin_elementwise_max(hb, zero4); \
    A = f32x4{T.z, T.z, T.z, T.z} * ha + A; \
    B = f32x4{T.z, T.z, T.z, T.z} * hb + B; }
  for (int node = 0; node < nn; ++node) {
    int deg = __builtin_amdgcn_readlane(mydeg, node);
    int nq = (deg + 3) >> 2;
    f32x4 aA = zero4, aB = zero4, cA = zero4, cB = zero4;
    if (staged) {
      const float4* buf = &sbuf[wave][k + qg];
      int q = 0;
      for (; q + 1 < nq; q += 2) {     // 2 ds_reads in flight
        float4 t0 = buf[4 * q];
        float4 t1 = buf[4 * q + 4];
        EDGE_Q(t0, aA, aB)
        EDGE_Q(t1, cA, cB)
      }
      if (q < nq) {
        float4 t0 = buf[4 * q];
        EDGE_Q(t0, aA, aB)
      }
    } else {                 // rare oversize strip: direct global path
      for (int q = 0; q < nq; ++q) {
        unsigned off = ssrc16[rs0 + k + 4 * q + qg];
        float4 t = *(const float4*)(tdc + off);
        EDGE_Q(t, aA, aB)
      }
    }
    k += nq * 4;
#pragma unroll
    for (int c = 0; c < 4; ++c) { aA[c] += cA[c]; aB[c] += cB[c]; }
    // reduce across the 4 quarter-waves
    f32x4 tA, tB;
#pragma unroll
    for (int c = 0; c < 4; ++c) {
      float v = aA[c] + __shfl_xor(aA[c], 16);
      tA[c] = v + __shfl_xor(v, 32);
      float u = aB[c] + __shfl_xor(aB[c], 16);
      tB[c] = u + __shfl_xor(u, 32);
    }
    float tx = __int_as_float(__builtin_amdgcn_readlane(mx, node));
    float ty = __int_as_float(__builtin_amdgcn_readlane(my, node));
    float tz = __int_as_float(__builtin_amdgcn_readlane(mz, node));
    f32x4 ha = f32x4{ty, ty, ty, ty} * w1a + bba;
    f32x4 hb = f32x4{ty, ty, ty, ty} * w1b + bbb;
    ha = f32x4{tx, tx, tx, tx} * w0a + ha;
    hb = f32x4{tx, tx, tx, tx} * w0b + hb;
    ha = __builtin_elementwise_max(ha, zero4);
    hb = __builtin_elementwise_max(hb, zero4);
    f32x4 rA = f32x4{tz, tz, tz, tz} * ha + tA;   // + self-loop term
    f32x4 rB = f32x4{tz, tz, tz, tz} * hb + tB;
    if (qg == 0) {
      uint4 o;
      o.x = ((unsigned)f2b(tz * rA[1]) << 16) | f2b(tz * rA[0]);
      o.y = ((unsigned)f2b(tz * rA[3]) << 16) | f2b(tz * rA[2]);
      o.z = ((unsigned)f2b(tz * rB[1]) << 16) | f2b(tz * rB[0]);
      o.w = ((unsigned)f2b(tz * rB[3]) << 16) | f2b(tz * rB[2]);
      *(uint4*)&m_b[(unsigned)(i0 + node) * 64 + sl * 4] = o;
    }
  }
#undef EDGE_Q
}

// ---------------- fused layer-2 transform + mean-pool + FC head (block per graph) ----------
__global__ void __launch_bounds__(256) k_t2pool(
    const unsigned* __restrict__ m_b, const unsigned* __restrict__ w2f,
    const float* __restrict__ b2, const int* __restrict__ gstart,
    const float* __restrict__ fc1W, const float* __restrict__ fc1b,
    const float* __restrict__ fc2W, const float* __restrict__ fc2b,
    float* __restrict__ out, int N, int G) {
  __shared__ unsigned W[16384];     // 64 KiB: hi + lo frags
  __shared__ float pool[16][HD];    // 8 KiB
  __shared__ float ps[HD];
  __shared__ float rsh[HD];
  int g = blockIdx.x;
  for (int u = threadIdx.x; u < 4096; u += 256)
    *(uint4*)&W[u * 4] = *(const uint4*)&w2f[u * 4];
  for (int u = threadIdx.x; u < 16 * HD; u += 256) ((float*)pool)[u] = 0.f;
  const int lane = threadIdx.x & 63;
  const int wave = threadIdx.x >> 6;
  const int col = lane & 15;
  const int kg = lane >> 4;
  float bb[8];
#pragma unroll
  for (int c = 0; c < 8; ++c) bb[c] = b2[c * 16 + col];
  int s0 = gstart[g], e0 = gstart[g + 1];
  int ntiles = (e0 - s0 + 15) >> 4;
  float pacc[8];
#pragma unroll
  for (int c = 0; c < 8; ++c) pacc[c] = 0.f;
  __syncthreads();
  for (int tile = wave; tile < ntiles; tile += 4) {
    int rbase = s0 + tile * 16;
    int arow = rbase + col;
    if (arow >= N) arow = N - 1;
    f32x4 acc[8];
#pragma unroll
    for (int c = 0; c < 8; ++c) acc[c] = f32x4{0.f, 0.f, 0.f, 0.f};
#pragma unroll
    for (int s = 0; s < 4; ++s) {
      uint4 av = *(const uint4*)&m_b[((size_t)arow << 6) + s * 16 + kg * 4];
      s16x8 A = *(s16x8*)&av;
#pragma unroll
      for (int c = 0; c < 8; ++c) {
        int f = (c * 4 + s) * 64 + lane;
        s16x8 Bh = *(s16x8*)&W[f * 4];
        s16x8 Bl = *(s16x8*)&W[8192 + f * 4];
        acc[c] = __builtin_amdgcn_mfma_f32_16x16x32_bf16(A, Bh, acc[c], 0, 0, 0);
        acc[c] = __builtin_amdgcn_mfma_f32_16x16x32_bf16(A, Bl, acc[c], 0, 0, 0);
      }
    }
    int orow = rbase + kg * 4;
#pragma unroll
    for (int c = 0; c < 8; ++c) {
#pragma unroll
      for (int r = 0; r < 4; ++r) {
        if (orow + r < e0) pacc[c] += fmaxf(acc[c][r] + bb[c], 0.f);
      }
    }
  }
#pragma unroll
  for (int c = 0; c < 8; ++c) pool[wave * 4 + kg][c * 16 + col] = pacc[c];
  __syncthreads();
  int j = threadIdx.x;
  if (j < HD) {
    float a = 0.f;
#pragma unroll
    for (int r = 0; r < 16; ++r) a += pool[r][j];
    float cg = (float)(e0 - s0);
    cg = cg < 1.f ? 1.f : cg;
    ps[j] = a / cg;
  }
  __syncthreads();
  if (j < HD) {
    float a = fc1b[j];
#pragma unroll 4
    for (int k = 0; k < HD; ++k) a = fmaf(ps[k], fc1W[k * HD + j], a);
    rsh[j] = fmaxf(a, 0.f) * fc2W[j];
  }
  __syncthreads();
  for (int off = 64; off > 0; off >>= 1) {
    if (j < off) rsh[j] += rsh[j + off];
    __syncthreads();
  }
  if (j == 0) out[g] = rsh[0] + fc2b[0];
}

extern "C" void kernel_launch(void* const* d_in, const int* in_sizes, int n_in,
                              void* d_out, int out_size, void* d_ws, size_t ws_size,
                              hipStream_t stream) {
  const float* x    = (const float*)d_in[0];
  const int* esrc   = (const int*)d_in[1];
  const int* edst   = (const int*)d_in[2];
  const int* bids   = (const int*)d_in[3];
  const float* W1   = (const float*)d_in[5];
  const float* b1   = (const float*)d_in[6];
  const float* W2   = (const float*)d_in[7];
  const float* b2   = (const float*)d_in[8];
  const float* fc1W = (const float*)d_in[9];
  const float* fc1b = (const float*)d_in[10];
  const float* fc2W = (const float*)d_in[11];
  const float* fc2b = (const float*)d_in[12];
  float* out = (float*)d_out;

  const int N = in_sizes[0] / 2;
  const int E = in_sizes[1];
  const int G = out_size;

  const int NB = idiv(N, BNODES);       // buckets (391 for N=100K)
  const int M = NB * BINBLK;            // count-matrix size (~100K)
  const int chunk = idiv(E, BINBLK);

  char* w = (char*)d_ws;
  size_t o = 0;
  auto take = [&](size_t b) -> char* {
    char* p = w + o;
    o = (o + b + 255) & ~(size_t)255;
    return p;
  };
  int*      cntm      = (int*)     take((size_t)M * 4);
  int*      scanM     = (int*)     take((size_t)M * 4);
  int*      part      = (int*)     take(4096);
  unsigned* recs      = (unsigned*)take((size_t)E * 4);
  unsigned* ssrc16    = (unsigned*)take((size_t)(E + 3 * (size_t)N + 512) * 4);
  int*      cnt       = (int*)     take((size_t)N * 4);
  int*      row_start = (int*)     take((size_t)N * 4);
  float*    dinv      = (float*)   take((size_t)N * 4);
  float*    xs        = (float*)   take((size_t)N * 8);
  float*    td        = (float*)   take((size_t)(N + 1) * 16);  // +sentinel row
  int*      gstart    = (int*)     take((size_t)(G + 1) * 4);
  unsigned* m_b       = (unsigned*)take((size_t)N * 64 * 4);    // bf16-packed m
  unsigned* w2f       = (unsigned*)take(16384 * 4);             // frag-linear W2 hi+lo

  int nbM = idiv(M, 1024);
  k_w2t_bincount<<<8 + BINBLK, 256, 0, stream>>>(W2, w2f, (float4*)td, edst,
                                                 cntm, E, NB, chunk, N);
  k_scan1<<<nbM, 256, 0, stream>>>(cntm, part, M);
  k_scan2<<<1, 1024, 0, stream>>>(part, nbM);
  k_scan3<<<nbM, 256, 0, stream>>>(cntm, part, scanM, M);
  k_binscatter<<<BINBLK, 256, 0, stream>>>(esrc, edst, scanM, recs, E, NB, chunk);
  k_bucketsort<<<NB, 256, 0, stream>>>(recs, scanM, x, bids, ssrc16, row_start,
                                       cnt, dinv, (float2*)xs, gstart, NB, N, G, E);
  k_aggx2<<<idiv(N, 256), 256, 0, stream>>>(row_start, cnt, ssrc16, (const float2*)xs,
                                            dinv, (float4*)td, N);
  int waves = idiv(N, PER);
  k_aggh<<<idiv(waves, 4), 256, 0, stream>>>(row_start, cnt, ssrc16, (const float4*)td,
                                             W1, b1, m_b, N);
  k_t2pool<<<G, 256, 0, stream>>>(m_b, w2f, b2, gstart, fc1W, fc1b, fc2W, fc2b, out, N, G);
}

// Round 22
// 118.237 us; speedup vs baseline: 1.1224x; 1.1224x over previous
//
#include <hip/hip_runtime.h>
#include <stdint.h>

#define HD 128
#define BSH 8        // bucket = 256 dst nodes
#define BNODES 256
#define PER 4        // nodes per wave in k_aggh
#define SCAP 128     // staged edge capacity per wave
#define BINBLK 256   // binning grid

typedef float f32x4 __attribute__((ext_vector_type(4)));
typedef short s16x8 __attribute__((ext_vector_type(8)));

static inline int idiv(int a, int b) { return (a + b - 1) / b; }

__device__ __forceinline__ unsigned short f2b(float f) {
  unsigned u = __float_as_uint(f);
  return (unsigned short)((u + 0x7fffu + ((u >> 16) & 1u)) >> 16);
}

// ---------------- fused: W2 frag transform (blocks 0..7) + bucket histogram (8..) ----
__global__ void __launch_bounds__(256) k_w2t_bincount(
    const float* __restrict__ W2, unsigned* __restrict__ w2f,
    float4* __restrict__ td, const int* __restrict__ edst,
    int* __restrict__ cntm, int E, int NB, int chunk, int N) {
  if (blockIdx.x < 8) {
    int f = blockIdx.x * 256 + threadIdx.x;
    if (f == 0) td[N] = make_float4(0.f, 0.f, 0.f, 0.f);  // sentinel row
    if (f >= 2048) return;
    int c = f >> 8, s = (f >> 6) & 3, lane = f & 63;
    int col = c * 16 + (lane & 15);
    int kb = s * 32 + (lane >> 4) * 8;
    unsigned hi4[4], lo4[4];
#pragma unroll
    for (int j = 0; j < 4; ++j) {
      float w0 = W2[(kb + 2 * j) * HD + col];
      float w1 = W2[(kb + 2 * j + 1) * HD + col];
      unsigned short h0 = f2b(w0), h1 = f2b(w1);
      float r0 = w0 - __uint_as_float((unsigned)h0 << 16);
      float r1 = w1 - __uint_as_float((unsigned)h1 << 16);
      unsigned short l0 = f2b(r0), l1 = f2b(r1);
      hi4[j] = ((unsigned)h1 << 16) | h0;
      lo4[j] = ((unsigned)l1 << 16) | l0;
    }
    *(uint4*)&w2f[f * 4] = make_uint4(hi4[0], hi4[1], hi4[2], hi4[3]);
    *(uint4*)&w2f[8192 + f * 4] = make_uint4(lo4[0], lo4[1], lo4[2], lo4[3]);
    return;
  }
  __shared__ int hist[512];
  int blk = blockIdx.x - 8;
  for (int b = threadIdx.x; b < 512; b += 256) hist[b] = 0;
  __syncthreads();
  int s0 = blk * chunk, s1 = min(E, s0 + chunk);
  for (int k = s0 + threadIdx.x; k < s1; k += 256)
    atomicAdd(&hist[edst[k] >> BSH], 1);
  __syncthreads();
  for (int b = threadIdx.x; b < NB; b += 256)
    cntm[(size_t)b * BINBLK + blk] = hist[b];
}

// ---------------- exclusive scan over M elements (3 kernels, coalesced) ----------
__global__ void k_scan1(const int* __restrict__ cnt, int* __restrict__ part, int N) {
  __shared__ int sh[256];
  int t = threadIdx.x;
  int base = blockIdx.x * 1024 + t * 4;
  int s = 0;
#pragma unroll
  for (int u = 0; u < 4; ++u) { int idx = base + u; if (idx < N) s += cnt[idx]; }
  sh[t] = s; __syncthreads();
  for (int off = 128; off > 0; off >>= 1) { if (t < off) sh[t] += sh[t + off]; __syncthreads(); }
  if (t == 0) part[blockIdx.x] = sh[0];
}

__global__ void k_scan2(int* part, int nb) {
  __shared__ int sh[1024];
  int t = threadIdx.x;
  int v = (t < nb) ? part[t] : 0;
  sh[t] = v;
  __syncthreads();
  for (int off = 1; off < 1024; off <<= 1) {
    int add = (t >= off) ? sh[t - off] : 0;
    __syncthreads();
    sh[t] += add;
    __syncthreads();
  }
  if (t < nb) part[t] = sh[t] - v;
}

__global__ void k_scan3(const int* __restrict__ cnt, const int* __restrict__ part,
                        int* __restrict__ out, int N) {
  __shared__ int sa[256], sb[256];
  int t = threadIdx.x;
  int base = blockIdx.x * 1024 + t * 4;
  int v[4]; int s = 0;
#pragma unroll
  for (int u = 0; u < 4; ++u) { int idx = base + u; v[u] = (idx < N) ? cnt[idx] : 0; s += v[u]; }
  sa[t] = s; __syncthreads();
  int* cur = sa; int* nxt = sb;
  for (int off = 1; off < 256; off <<= 1) {
    int val = cur[t] + ((t >= off) ? cur[t - off] : 0);
    nxt[t] = val; __syncthreads();
    int* tmp = cur; cur = nxt; nxt = tmp;
  }
  int excl = cur[t] - s + part[blockIdx.x];
#pragma unroll
  for (int u = 0; u < 4; ++u) {
    int idx = base + u;
    if (idx < N) { out[idx] = excl; excl += v[u]; }
  }
}

// ---------------- pass 2: bin edges into bucket-grouped records ----------------
__global__ void __launch_bounds__(256) k_binscatter(const int* __restrict__ esrc,
                                                    const int* __restrict__ edst,
                                                    const int* __restrict__ scanM,
                                                    unsigned* __restrict__ recs,
                                                    int E, int NB, int chunk) {
  __shared__ int cur[512];
  int blk = blockIdx.x;
  for (int b = threadIdx.x; b < NB; b += 256) cur[b] = scanM[(size_t)b * BINBLK + blk];
  __syncthreads();
  int s0 = blk * chunk, s1 = min(E, s0 + chunk);
  for (int k = s0 + threadIdx.x; k < s1; k += 256) {
    int d = edst[k], s = esrc[k];
    int b = d >> BSH;
    int pos = atomicAdd(&cur[b], 1);
    recs[pos] = ((unsigned)(d & (BNODES - 1)) << 23) | (unsigned)s;
  }
}

// ---------------- pass 3: per-bucket counting sort -> even-padded CSR + node prep ----
__global__ void __launch_bounds__(256) k_bucketsort(const unsigned* __restrict__ recs,
                                                    const int* __restrict__ scanM,
                                                    const float* __restrict__ x,
                                                    const int* __restrict__ bids,
                                                    unsigned* __restrict__ ssrc16,
                                                    int* __restrict__ row_start,
                                                    int* __restrict__ cnt,
                                                    float* __restrict__ dinv,
                                                    float2* __restrict__ xs,
                                                    int* __restrict__ gstart,
                                                    int NB, int N, int G, int E) {
  __shared__ int count[BNODES], excl[BNODES], cur[BNODES], psum[32];
  int b = blockIdx.x;
  int t = threadIdx.x;
  count[t] = 0;
  __syncthreads();
  int rs = scanM[(size_t)b * BINBLK];
  int re = (b == NB - 1) ? E : scanM[(size_t)(b + 1) * BINBLK];
  int base_p = rs + b * BNODES;
  for (int k = rs + t; k < re; k += 256) atomicAdd(&count[recs[k] >> 23], 1);
  __syncthreads();
  if (t < 32) {
    int s = 0;
#pragma unroll
    for (int u = 0; u < 8; ++u) s += (count[t * 8 + u] + 1) & ~1;
    psum[t] = s;
  }
  __syncthreads();
  if (t == 0) {
    int run = 0;
    for (int d = 0; d < 32; ++d) { int v = psum[d]; psum[d] = run; run += v; }
  }
  __syncthreads();
  if (t < 32) {
    int run = psum[t];
#pragma unroll
    for (int u = 0; u < 8; ++u) {
      excl[t * 8 + u] = run;
      run += (count[t * 8 + u] + 1) & ~1;
    }
  }
  __syncthreads();
  {
    int d = t;
    int i = b * BNODES + d;
    if (i < N) {
      cnt[i] = count[d];
      row_start[i] = base_p + excl[d];
      if (count[d] & 1)   // sentinel pad slot
        ssrc16[base_p + excl[d] + count[d]] = (unsigned)N << 4;
      float di = rsqrtf((float)(count[d] + 1));
      dinv[i] = di;
      float2 xv = *(const float2*)&x[2 * i];
      xs[i] = make_float2(di * xv.x, di * xv.y);
      int g = bids[i];
      if (i == 0)
        for (int gg = 0; gg <= g; ++gg) gstart[gg] = 0;
      int gn = (i == N - 1) ? G : bids[i + 1];
      for (int gg = g + 1; gg <= gn; ++gg) gstart[gg] = i + 1;
    }
    cur[d] = excl[d];
  }
  __syncthreads();
  for (int k = rs + t; k < re; k += 256) {
    unsigned r = recs[k];
    int dl = r >> 23;
    int pos = base_p + atomicAdd(&cur[dl], 1);
    ssrc16[pos] = (r & 0x007fffffu) << 4;   // byte offset into td (16B rows)
  }
}

// ---------------- layer-1 aggregation -> td = (t0, t1, dinv, 0) ----------------
__global__ void k_aggx2(const int* __restrict__ row_start, const int* __restrict__ cnt,
                        const unsigned* __restrict__ ssrc16, const float2* __restrict__ xs,
                        const float* __restrict__ dinv, float4* __restrict__ td, int N) {
  int i = blockIdx.x * 256 + threadIdx.x;
  if (i >= N) return;
  int rs = row_start[i], re = rs + cnt[i];
  float a0 = 0.f, a1 = 0.f, b0 = 0.f, b1 = 0.f;
  int k = rs;
  for (; k + 3 < re; k += 4) {
    unsigned v0 = ssrc16[k] >> 4, v1 = ssrc16[k + 1] >> 4;
    unsigned v2 = ssrc16[k + 2] >> 4, v3 = ssrc16[k + 3] >> 4;
    float2 p0 = xs[v0], p1 = xs[v1], p2 = xs[v2], p3 = xs[v3];
    a0 += p0.x + p1.x; a1 += p0.y + p1.y;
    b0 += p2.x + p3.x; b1 += p2.y + p3.y;
  }
  for (; k < re; ++k) {
    float2 p = xs[ssrc16[k] >> 4];
    a0 += p.x; a1 += p.y;
  }
  a0 += b0; a1 += b1;
  float2 self = xs[i];
  float di = dinv[i];
  td[i] = make_float4(di * (a0 + self.x), di * (a1 + self.y), di, 0.f);
}

// ---------------- fused layer-1 transform + layer-2 aggregation ----------------
// Wave = strip of PER nodes (even-padded contiguous CSR within one bucket).
// Stage the strip (<=SCAP edges) into per-wave LDS with 2 64-wide gathers, then
// consume 2 edge-pairs per iteration (2 ds_read_b128 in flight, 2 indep accs):
// low half-wave = even edge, high half = odd edge; lane owns a feature quad.
__global__ void __launch_bounds__(256) k_aggh(
    const int* __restrict__ row_start, const int* __restrict__ cnt,
    const unsigned* __restrict__ ssrc16, const float4* __restrict__ td,
    const float* __restrict__ W1, const float* __restrict__ b1,
    unsigned* __restrict__ m_b, int N) {
  __shared__ float4 sbuf[4][SCAP];   // 8 KiB, per-wave slabs
  int wave = threadIdx.x >> 6;
  int lane = threadIdx.x & 63;
  int wid = blockIdx.x * 4 + wave;
  int i0 = wid * PER;
  if (i0 >= N) return;
  int nn = min(N - i0, PER);
  int hl = lane >> 5;                 // half-wave id
  int fq = (lane & 31) * 4;           // feature quad base
  f32x4 w0 = *(const f32x4*)&W1[fq];
  f32x4 w1 = *(const f32x4*)&W1[HD + fq];
  f32x4 bb = *(const f32x4*)&b1[fq];
  int mydeg = (lane < nn) ? cnt[i0 + lane] : 0;
  int myrow = (lane < nn) ? row_start[i0 + lane] : 0;
  float4 mytd = (lane < nn) ? td[i0 + lane] : make_float4(0.f, 0.f, 0.f, 0.f);
  int mx = __float_as_int(mytd.x), my = __float_as_int(mytd.y), mz = __float_as_int(mytd.z);
  int rs0 = __builtin_amdgcn_readfirstlane(myrow);
  int last = nn - 1;
  int rsEnd = __builtin_amdgcn_readlane(myrow, last) +
              ((__builtin_amdgcn_readlane(mydeg, last) + 1) & ~1);
  int total = rsEnd - rs0;
  const char* tdc = (const char*)td;
  bool staged = (total <= SCAP);
  if (staged) {
#pragma unroll
    for (int w = 0; w < SCAP / 64; ++w) {
      int sl = w * 64 + lane;
      if (sl < total) {
        unsigned off = ssrc16[rs0 + sl];
        sbuf[wave][sl] = *(const float4*)(tdc + off);
      }
    }
  }
  int k = 0;
  const f32x4 zero4 = {0.f, 0.f, 0.f, 0.f};
#define EDGE_F(T, ACC) { \
    f32x4 h = f32x4{T.y, T.y, T.y, T.y} * w1 + bb; \
    h = f32x4{T.x, T.x, T.x, T.x} * w0 + h; \
    h = __builtin_elementwise_max(h, zero4); \
    ACC = f32x4{T.z, T.z, T.z, T.z} * h + ACC; }
  for (int node = 0; node < nn; ++node) {
    int deg = __builtin_amdgcn_readlane(mydeg, node);
    int np = (deg + 1) >> 1;
    f32x4 acc = zero4, acc2 = zero4;
    if (staged) {
      const float4* buf = &sbuf[wave][k + hl];
      int p = 0;
      for (; p + 1 < np; p += 2) {        // 2 ds_reads in flight, 2 indep accs
        float4 t0 = buf[2 * p];
        float4 t1 = buf[2 * p + 2];
        EDGE_F(t0, acc)
        EDGE_F(t1, acc2)
      }
      if (p < np) {
        float4 t0 = buf[2 * p];
        EDGE_F(t0, acc)
      }
    } else {                 // rare oversize strip: direct global path
      for (int p = 0; p < np; ++p) {
        unsigned off = ssrc16[rs0 + k + 2 * p + hl];
        float4 t = *(const float4*)(tdc + off);
        EDGE_F(t, acc)
      }
    }
    k += np * 2;
#pragma unroll
    for (int c = 0; c < 4; ++c) acc[c] += acc2[c];
    f32x4 tot;
#pragma unroll
    for (int c = 0; c < 4; ++c) tot[c] = acc[c] + __shfl_xor(acc[c], 32);
    float tx = __int_as_float(__builtin_amdgcn_readlane(mx, node));
    float ty = __int_as_float(__builtin_amdgcn_readlane(my, node));
    float tz = __int_as_float(__builtin_amdgcn_readlane(mz, node));
    f32x4 h = f32x4{ty, ty, ty, ty} * w1 + bb;
    h = f32x4{tx, tx, tx, tx} * w0 + h;
    h = __builtin_elementwise_max(h, zero4);
    f32x4 r = f32x4{tz, tz, tz, tz} * h + tot;   // + self-loop term
    float v0 = (hl ? r[2] : r[0]) * tz;
    float v1 = (hl ? r[3] : r[1]) * tz;
    int j = hl ? (2 * (lane - 32) + 1) : (2 * lane);
    m_b[(unsigned)(i0 + node) * 64 + j] = ((unsigned)f2b(v1) << 16) | f2b(v0);
  }
#undef EDGE_F
}

// ---------------- fused layer-2 transform + mean-pool + FC head (block per graph) ----------
__global__ void __launch_bounds__(256) k_t2pool(
    const unsigned* __restrict__ m_b, const unsigned* __restrict__ w2f,
    const float* __restrict__ b2, const int* __restrict__ gstart,
    const float* __restrict__ fc1W, const float* __restrict__ fc1b,
    const float* __restrict__ fc2W, const float* __restrict__ fc2b,
    float* __restrict__ out, int N, int G) {
  __shared__ unsigned W[16384];     // 64 KiB: hi + lo frags
  __shared__ float pool[16][HD];    // 8 KiB
  __shared__ float ps[HD];
  __shared__ float rsh[HD];
  int g = blockIdx.x;
  for (int u = threadIdx.x; u < 4096; u += 256)
    *(uint4*)&W[u * 4] = *(const uint4*)&w2f[u * 4];
  for (int u = threadIdx.x; u < 16 * HD; u += 256) ((float*)pool)[u] = 0.f;
  const int lane = threadIdx.x & 63;
  const int wave = threadIdx.x >> 6;
  const int col = lane & 15;
  const int kg = lane >> 4;
  float bb[8];
#pragma unroll
  for (int c = 0; c < 8; ++c) bb[c] = b2[c * 16 + col];
  int s0 = gstart[g], e0 = gstart[g + 1];
  int ntiles = (e0 - s0 + 15) >> 4;
  float pacc[8];
#pragma unroll
  for (int c = 0; c < 8; ++c) pacc[c] = 0.f;
  __syncthreads();
  for (int tile = wave; tile < ntiles; tile += 4) {
    int rbase = s0 + tile * 16;
    int arow = rbase + col;
    if (arow >= N) arow = N - 1;
    f32x4 acc[8];
#pragma unroll
    for (int c = 0; c < 8; ++c) acc[c] = f32x4{0.f, 0.f, 0.f, 0.f};
#pragma unroll
    for (int s = 0; s < 4; ++s) {
      uint4 av = *(const uint4*)&m_b[((size_t)arow << 6) + s * 16 + kg * 4];
      s16x8 A = *(s16x8*)&av;
#pragma unroll
      for (int c = 0; c < 8; ++c) {
        int f = (c * 4 + s) * 64 + lane;
        s16x8 Bh = *(s16x8*)&W[f * 4];
        s16x8 Bl = *(s16x8*)&W[8192 + f * 4];
        acc[c] = __builtin_amdgcn_mfma_f32_16x16x32_bf16(A, Bh, acc[c], 0, 0, 0);
        acc[c] = __builtin_amdgcn_mfma_f32_16x16x32_bf16(A, Bl, acc[c], 0, 0, 0);
      }
    }
    int orow = rbase + kg * 4;
#pragma unroll
    for (int c = 0; c < 8; ++c) {
#pragma unroll
      for (int r = 0; r < 4; ++r) {
        if (orow + r < e0) pacc[c] += fmaxf(acc[c][r] + bb[c], 0.f);
      }
    }
  }
#pragma unroll
  for (int c = 0; c < 8; ++c) pool[wave * 4 + kg][c * 16 + col] = pacc[c];
  __syncthreads();
  int j = threadIdx.x;
  if (j < HD) {
    float a = 0.f;
#pragma unroll
    for (int r = 0; r < 16; ++r) a += pool[r][j];
    float cg = (float)(e0 - s0);
    cg = cg < 1.f ? 1.f : cg;
    ps[j] = a / cg;
  }
  __syncthreads();
  if (j < HD) {
    float a = fc1b[j];
#pragma unroll 4
    for (int k = 0; k < HD; ++k) a = fmaf(ps[k], fc1W[k * HD + j], a);
    rsh[j] = fmaxf(a, 0.f) * fc2W[j];
  }
  __syncthreads();
  for (int off = 64; off > 0; off >>= 1) {
    if (j < off) rsh[j] += rsh[j + off];
    __syncthreads();
  }
  if (j == 0) out[g] = rsh[0] + fc2b[0];
}

extern "C" void kernel_launch(void* const* d_in, const int* in_sizes, int n_in,
                              void* d_out, int out_size, void* d_ws, size_t ws_size,
                              hipStream_t stream) {
  const float* x    = (const float*)d_in[0];
  const int* esrc   = (const int*)d_in[1];
  const int* edst   = (const int*)d_in[2];
  const int* bids   = (const int*)d_in[3];
  const float* W1   = (const float*)d_in[5];
  const float* b1   = (const float*)d_in[6];
  const float* W2   = (const float*)d_in[7];
  const float* b2   = (const float*)d_in[8];
  const float* fc1W = (const float*)d_in[9];
  const float* fc1b = (const float*)d_in[10];
  const float* fc2W = (const float*)d_in[11];
  const float* fc2b = (const float*)d_in[12];
  float* out = (float*)d_out;

  const int N = in_sizes[0] / 2;
  const int E = in_sizes[1];
  const int G = out_size;

  const int NB = idiv(N, BNODES);       // buckets (391 for N=100K)
  const int M = NB * BINBLK;            // count-matrix size (~100K)
  const int chunk = idiv(E, BINBLK);

  char* w = (char*)d_ws;
  size_t o = 0;
  auto take = [&](size_t b) -> char* {
    char* p = w + o;
    o = (o + b + 255) & ~(size_t)255;
    return p;
  };
  int*      cntm      = (int*)     take((size_t)M * 4);
  int*      scanM     = (int*)     take((size_t)M * 4);
  int*      part      = (int*)     take(4096);
  unsigned* recs      = (unsigned*)take((size_t)E * 4);
  unsigned* ssrc16    = (unsigned*)take((size_t)(E + N + 256) * 4);
  int*      cnt       = (int*)     take((size_t)N * 4);
  int*      row_start = (int*)     take((size_t)N * 4);
  float*    dinv      = (float*)   take((size_t)N * 4);
  float*    xs        = (float*)   take((size_t)N * 8);
  float*    td        = (float*)   take((size_t)(N + 1) * 16);  // +sentinel row
  int*      gstart    = (int*)     take((size_t)(G + 1) * 4);
  unsigned* m_b       = (unsigned*)take((size_t)N * 64 * 4);    // bf16-packed m
  unsigned* w2f       = (unsigned*)take(16384 * 4);             // frag-linear W2 hi+lo

  int nbM = idiv(M, 1024);
  k_w2t_bincount<<<8 + BINBLK, 256, 0, stream>>>(W2, w2f, (float4*)td, edst,
                                                 cntm, E, NB, chunk, N);
  k_scan1<<<nbM, 256, 0, stream>>>(cntm, part, M);
  k_scan2<<<1, 1024, 0, stream>>>(part, nbM);
  k_scan3<<<nbM, 256, 0, stream>>>(cntm, part, scanM, M);
  k_binscatter<<<BINBLK, 256, 0, stream>>>(esrc, edst, scanM, recs, E, NB, chunk);
  k_bucketsort<<<NB, 256, 0, stream>>>(recs, scanM, x, bids, ssrc16, row_start,
                                       cnt, dinv, (float2*)xs, gstart, NB, N, G, E);
  k_aggx2<<<idiv(N, 256), 256, 0, stream>>>(row_start, cnt, ssrc16, (const float2*)xs,
                                            dinv, (float4*)td, N);
  int waves = idiv(N, PER);
  k_aggh<<<idiv(waves, 4), 256, 0, stream>>>(row_start, cnt, ssrc16, (const float4*)td,
                                             W1, b1, m_b, N);
  k_t2pool<<<G, 256, 0, stream>>>(m_b, w2f, b2, gstart, fc1W, fc1b, fc2W, fc2b, out, N, G);
}

// Round 23
// 117.926 us; speedup vs baseline: 1.1254x; 1.0026x over previous
//
#include <hip/hip_runtime.h>
#include <stdint.h>

#define HD 128
#define BSH 8        // bucket = 256 dst nodes
#define BNODES 256
#define PER 4        // nodes per wave in k_aggh
#define SCAP 128     // staged edge capacity per wave
#define BINBLK 256   // binning grid

typedef float f32x4 __attribute__((ext_vector_type(4)));
typedef short s16x8 __attribute__((ext_vector_type(8)));

static inline int idiv(int a, int b) { return (a + b - 1) / b; }

__device__ __forceinline__ unsigned short f2b(float f) {
  unsigned u = __float_as_uint(f);
  return (unsigned short)((u + 0x7fffu + ((u >> 16) & 1u)) >> 16);
}

// ---------------- fused: W2 frag transform (blocks 0..7) + bucket histogram (8..) ----
__global__ void __launch_bounds__(256) k_w2t_bincount(
    const float* __restrict__ W2, unsigned* __restrict__ w2f,
    float4* __restrict__ td, const int* __restrict__ edst,
    int* __restrict__ cntm, int E, int NB, int chunk, int N) {
  if (blockIdx.x < 8) {
    int f = blockIdx.x * 256 + threadIdx.x;
    if (f == 0) td[N] = make_float4(0.f, 0.f, 0.f, 0.f);  // sentinel row
    if (f >= 2048) return;
    int c = f >> 8, s = (f >> 6) & 3, lane = f & 63;
    int col = c * 16 + (lane & 15);
    int kb = s * 32 + (lane >> 4) * 8;
    unsigned hi4[4], lo4[4];
#pragma unroll
    for (int j = 0; j < 4; ++j) {
      float w0 = W2[(kb + 2 * j) * HD + col];
      float w1 = W2[(kb + 2 * j + 1) * HD + col];
      unsigned short h0 = f2b(w0), h1 = f2b(w1);
      float r0 = w0 - __uint_as_float((unsigned)h0 << 16);
      float r1 = w1 - __uint_as_float((unsigned)h1 << 16);
      unsigned short l0 = f2b(r0), l1 = f2b(r1);
      hi4[j] = ((unsigned)h1 << 16) | h0;
      lo4[j] = ((unsigned)l1 << 16) | l0;
    }
    *(uint4*)&w2f[f * 4] = make_uint4(hi4[0], hi4[1], hi4[2], hi4[3]);
    *(uint4*)&w2f[8192 + f * 4] = make_uint4(lo4[0], lo4[1], lo4[2], lo4[3]);
    return;
  }
  __shared__ int hist[512];
  int blk = blockIdx.x - 8;
  for (int b = threadIdx.x; b < 512; b += 256) hist[b] = 0;
  __syncthreads();
  int s0 = blk * chunk, s1 = min(E, s0 + chunk);
  for (int k = s0 + threadIdx.x; k < s1; k += 256)
    atomicAdd(&hist[edst[k] >> BSH], 1);
  __syncthreads();
  for (int b = threadIdx.x; b < NB; b += 256)
    cntm[(size_t)b * BINBLK + blk] = hist[b];
}

// ---------------- exclusive scan over M elements (3 kernels, coalesced) ----------
__global__ void k_scan1(const int* __restrict__ cnt, int* __restrict__ part, int N) {
  __shared__ int sh[256];
  int t = threadIdx.x;
  int base = blockIdx.x * 1024 + t * 4;
  int s = 0;
#pragma unroll
  for (int u = 0; u < 4; ++u) { int idx = base + u; if (idx < N) s += cnt[idx]; }
  sh[t] = s; __syncthreads();
  for (int off = 128; off > 0; off >>= 1) { if (t < off) sh[t] += sh[t + off]; __syncthreads(); }
  if (t == 0) part[blockIdx.x] = sh[0];
}

__global__ void k_scan2(int* part, int nb) {
  __shared__ int sh[1024];
  int t = threadIdx.x;
  int v = (t < nb) ? part[t] : 0;
  sh[t] = v;
  __syncthreads();
  for (int off = 1; off < 1024; off <<= 1) {
    int add = (t >= off) ? sh[t - off] : 0;
    __syncthreads();
    sh[t] += add;
    __syncthreads();
  }
  if (t < nb) part[t] = sh[t] - v;
}

__global__ void k_scan3(const int* __restrict__ cnt, const int* __restrict__ part,
                        int* __restrict__ out, int N) {
  __shared__ int sa[256], sb[256];
  int t = threadIdx.x;
  int base = blockIdx.x * 1024 + t * 4;
  int v[4]; int s = 0;
#pragma unroll
  for (int u = 0; u < 4; ++u) { int idx = base + u; v[u] = (idx < N) ? cnt[idx] : 0; s += v[u]; }
  sa[t] = s; __syncthreads();
  int* cur = sa; int* nxt = sb;
  for (int off = 1; off < 256; off <<= 1) {
    int val = cur[t] + ((t >= off) ? cur[t - off] : 0);
    nxt[t] = val; __syncthreads();
    int* tmp = cur; cur = nxt; nxt = tmp;
  }
  int excl = cur[t] - s + part[blockIdx.x];
#pragma unroll
  for (int u = 0; u < 4; ++u) {
    int idx = base + u;
    if (idx < N) { out[idx] = excl; excl += v[u]; }
  }
}

// ---------------- pass 2: bin edges into bucket-grouped records ----------------
__global__ void __launch_bounds__(256) k_binscatter(const int* __restrict__ esrc,
                                                    const int* __restrict__ edst,
                                                    const int* __restrict__ scanM,
                                                    unsigned* __restrict__ recs,
                                                    int E, int NB, int chunk) {
  __shared__ int cur[512];
  int blk = blockIdx.x;
  for (int b = threadIdx.x; b < NB; b += 256) cur[b] = scanM[(size_t)b * BINBLK + blk];
  __syncthreads();
  int s0 = blk * chunk, s1 = min(E, s0 + chunk);
  for (int k = s0 + threadIdx.x; k < s1; k += 256) {
    int d = edst[k], s = esrc[k];
    int b = d >> BSH;
    int pos = atomicAdd(&cur[b], 1);
    recs[pos] = ((unsigned)(d & (BNODES - 1)) << 23) | (unsigned)s;
  }
}

// ---------------- pass 3: per-bucket counting sort -> even-padded CSR + node prep ----
__global__ void __launch_bounds__(256) k_bucketsort(const unsigned* __restrict__ recs,
                                                    const int* __restrict__ scanM,
                                                    const float* __restrict__ x,
                                                    const int* __restrict__ bids,
                                                    unsigned* __restrict__ ssrc16,
                                                    int* __restrict__ row_start,
                                                    int* __restrict__ cnt,
                                                    float* __restrict__ dinv,
                                                    float2* __restrict__ xs,
                                                    int* __restrict__ gstart,
                                                    int NB, int N, int G, int E) {
  __shared__ int count[BNODES], excl[BNODES], cur[BNODES], psum[32];
  int b = blockIdx.x;
  int t = threadIdx.x;
  count[t] = 0;
  __syncthreads();
  int rs = scanM[(size_t)b * BINBLK];
  int re = (b == NB - 1) ? E : scanM[(size_t)(b + 1) * BINBLK];
  int base_p = rs + b * BNODES;
  for (int k = rs + t; k < re; k += 256) atomicAdd(&count[recs[k] >> 23], 1);
  __syncthreads();
  if (t < 32) {
    int s = 0;
#pragma unroll
    for (int u = 0; u < 8; ++u) s += (count[t * 8 + u] + 1) & ~1;
    psum[t] = s;
  }
  __syncthreads();
  if (t == 0) {
    int run = 0;
    for (int d = 0; d < 32; ++d) { int v = psum[d]; psum[d] = run; run += v; }
  }
  __syncthreads();
  if (t < 32) {
    int run = psum[t];
#pragma unroll
    for (int u = 0; u < 8; ++u) {
      excl[t * 8 + u] = run;
      run += (count[t * 8 + u] + 1) & ~1;
    }
  }
  __syncthreads();
  {
    int d = t;
    int i = b * BNODES + d;
    if (i < N) {
      cnt[i] = count[d];
      row_start[i] = base_p + excl[d];
      if (count[d] & 1)   // sentinel pad slot
        ssrc16[base_p + excl[d] + count[d]] = (unsigned)N << 4;
      float di = rsqrtf((float)(count[d] + 1));
      dinv[i] = di;
      float2 xv = *(const float2*)&x[2 * i];
      xs[i] = make_float2(di * xv.x, di * xv.y);
      int g = bids[i];
      if (i == 0)
        for (int gg = 0; gg <= g; ++gg) gstart[gg] = 0;
      int gn = (i == N - 1) ? G : bids[i + 1];
      for (int gg = g + 1; gg <= gn; ++gg) gstart[gg] = i + 1;
    }
    cur[d] = excl[d];
  }
  __syncthreads();
  for (int k = rs + t; k < re; k += 256) {
    unsigned r = recs[k];
    int dl = r >> 23;
    int pos = base_p + atomicAdd(&cur[dl], 1);
    ssrc16[pos] = (r & 0x007fffffu) << 4;   // byte offset into td (16B rows)
  }
}

// ---------------- layer-1 aggregation -> td = (t0, t1, dinv, 0) ----------------
__global__ void k_aggx2(const int* __restrict__ row_start, const int* __restrict__ cnt,
                        const unsigned* __restrict__ ssrc16, const float2* __restrict__ xs,
                        const float* __restrict__ dinv, float4* __restrict__ td, int N) {
  int i = blockIdx.x * 256 + threadIdx.x;
  if (i >= N) return;
  int rs = row_start[i], re = rs + cnt[i];
  float a0 = 0.f, a1 = 0.f, b0 = 0.f, b1 = 0.f;
  int k = rs;
  for (; k + 3 < re; k += 4) {
    unsigned v0 = ssrc16[k] >> 4, v1 = ssrc16[k + 1] >> 4;
    unsigned v2 = ssrc16[k + 2] >> 4, v3 = ssrc16[k + 3] >> 4;
    float2 p0 = xs[v0], p1 = xs[v1], p2 = xs[v2], p3 = xs[v3];
    a0 += p0.x + p1.x; a1 += p0.y + p1.y;
    b0 += p2.x + p3.x; b1 += p2.y + p3.y;
  }
  for (; k < re; ++k) {
    float2 p = xs[ssrc16[k] >> 4];
    a0 += p.x; a1 += p.y;
  }
  a0 += b0; a1 += b1;
  float2 self = xs[i];
  float di = dinv[i];
  td[i] = make_float4(di * (a0 + self.x), di * (a1 + self.y), di, 0.f);
}

// ---------------- fused layer-1 transform + layer-2 aggregation ----------------
// Wave = strip of PER nodes (even-padded contiguous CSR within one bucket).
// Stage the strip (<=SCAP edges) into per-wave LDS with 2 64-wide gathers, then
// consume 2 edge-pairs per iteration (2 ds_read_b128 in flight, 2 indep accs):
// low half-wave = even edge, high half = odd edge; lane owns a feature quad.
__global__ void __launch_bounds__(256) k_aggh(
    const int* __restrict__ row_start, const int* __restrict__ cnt,
    const unsigned* __restrict__ ssrc16, const float4* __restrict__ td,
    const float* __restrict__ W1, const float* __restrict__ b1,
    unsigned* __restrict__ m_b, int N) {
  __shared__ float4 sbuf[4][SCAP];   // 8 KiB, per-wave slabs
  int wave = threadIdx.x >> 6;
  int lane = threadIdx.x & 63;
  int wid = blockIdx.x * 4 + wave;
  int i0 = wid * PER;
  if (i0 >= N) return;
  int nn = min(N - i0, PER);
  int hl = lane >> 5;                 // half-wave id
  int fq = (lane & 31) * 4;           // feature quad base
  f32x4 w0 = *(const f32x4*)&W1[fq];
  f32x4 w1 = *(const f32x4*)&W1[HD + fq];
  f32x4 bb = *(const f32x4*)&b1[fq];
  int mydeg = (lane < nn) ? cnt[i0 + lane] : 0;
  int myrow = (lane < nn) ? row_start[i0 + lane] : 0;
  float4 mytd = (lane < nn) ? td[i0 + lane] : make_float4(0.f, 0.f, 0.f, 0.f);
  int mx = __float_as_int(mytd.x), my = __float_as_int(mytd.y), mz = __float_as_int(mytd.z);
  int rs0 = __builtin_amdgcn_readfirstlane(myrow);
  int last = nn - 1;
  int rsEnd = __builtin_amdgcn_readlane(myrow, last) +
              ((__builtin_amdgcn_readlane(mydeg, last) + 1) & ~1);
  int total = rsEnd - rs0;
  const char* tdc = (const char*)td;
  bool staged = (total <= SCAP);
  if (staged) {
#pragma unroll
    for (int w = 0; w < SCAP / 64; ++w) {
      int sl = w * 64 + lane;
      if (sl < total) {
        unsigned off = ssrc16[rs0 + sl];
        sbuf[wave][sl] = *(const float4*)(tdc + off);
      }
    }
  }
  int k = 0;
  const f32x4 zero4 = {0.f, 0.f, 0.f, 0.f};
#define EDGE_F(T, ACC) { \
    f32x4 h = f32x4{T.y, T.y, T.y, T.y} * w1 + bb; \
    h = f32x4{T.x, T.x, T.x, T.x} * w0 + h; \
    h = __builtin_elementwise_max(h, zero4); \
    ACC = f32x4{T.z, T.z, T.z, T.z} * h + ACC; }
  for (int node = 0; node < nn; ++node) {
    int deg = __builtin_amdgcn_readlane(mydeg, node);
    int np = (deg + 1) >> 1;
    f32x4 acc = zero4, acc2 = zero4;
    if (staged) {
      const float4* buf = &sbuf[wave][k + hl];
      int p = 0;
      for (; p + 1 < np; p += 2) {        // 2 ds_reads in flight, 2 indep accs
        float4 t0 = buf[2 * p];
        float4 t1 = buf[2 * p + 2];
        EDGE_F(t0, acc)
        EDGE_F(t1, acc2)
      }
      if (p < np) {
        float4 t0 = buf[2 * p];
        EDGE_F(t0, acc)
      }
    } else {                 // rare oversize strip: direct global path
      for (int p = 0; p < np; ++p) {
        unsigned off = ssrc16[rs0 + k + 2 * p + hl];
        float4 t = *(const float4*)(tdc + off);
        EDGE_F(t, acc)
      }
    }
    k += np * 2;
#pragma unroll
    for (int c = 0; c < 4; ++c) acc[c] += acc2[c];
    f32x4 tot;
#pragma unroll
    for (int c = 0; c < 4; ++c) tot[c] = acc[c] + __shfl_xor(acc[c], 32);
    float tx = __int_as_float(__builtin_amdgcn_readlane(mx, node));
    float ty = __int_as_float(__builtin_amdgcn_readlane(my, node));
    float tz = __int_as_float(__builtin_amdgcn_readlane(mz, node));
    f32x4 h = f32x4{ty, ty, ty, ty} * w1 + bb;
    h = f32x4{tx, tx, tx, tx} * w0 + h;
    h = __builtin_elementwise_max(h, zero4);
    f32x4 r = f32x4{tz, tz, tz, tz} * h + tot;   // + self-loop term
    float v0 = (hl ? r[2] : r[0]) * tz;
    float v1 = (hl ? r[3] : r[1]) * tz;
    int j = hl ? (2 * (lane - 32) + 1) : (2 * lane);
    m_b[(unsigned)(i0 + node) * 64 + j] = ((unsigned)f2b(v1) << 16) | f2b(v0);
  }
#undef EDGE_F
}

// ---------------- fused layer-2 transform + mean-pool + FC head (block per graph) ----------
__global__ void __launch_bounds__(256) k_t2pool(
    const unsigned* __restrict__ m_b, const unsigned* __restrict__ w2f,
    const float* __restrict__ b2, const int* __restrict__ gstart,
    const float* __restrict__ fc1W, const float* __restrict__ fc1b,
    const float* __restrict__ fc2W, const float* __restrict__ fc2b,
    float* __restrict__ out, int N, int G) {
  __shared__ unsigned W[16384];     // 64 KiB: hi + lo frags
  __shared__ float pool[16][HD];    // 8 KiB
  __shared__ float ps[HD];
  __shared__ float rsh[HD];
  int g = blockIdx.x;
  for (int u = threadIdx.x; u < 4096; u += 256)
    *(uint4*)&W[u * 4] = *(const uint4*)&w2f[u * 4];
  for (int u = threadIdx.x; u < 16 * HD; u += 256) ((float*)pool)[u] = 0.f;
  const int lane = threadIdx.x & 63;
  const int wave = threadIdx.x >> 6;
  const int col = lane & 15;
  const int kg = lane >> 4;
  float bb[8];
#pragma unroll
  for (int c = 0; c < 8; ++c) bb[c] = b2[c * 16 + col];
  int s0 = gstart[g], e0 = gstart[g + 1];
  int ntiles = (e0 - s0 + 15) >> 4;
  float pacc[8];
#pragma unroll
  for (int c = 0; c < 8; ++c) pacc[c] = 0.f;
  __syncthreads();
  for (int tile = wave; tile < ntiles; tile += 4) {
    int rbase = s0 + tile * 16;
    int arow = rbase + col;
    if (arow >= N) arow = N - 1;
    f32x4 acc[8];
#pragma unroll
    for (int c = 0; c < 8; ++c) acc[c] = f32x4{0.f, 0.f, 0.f, 0.f};
#pragma unroll
    for (int s = 0; s < 4; ++s) {
      uint4 av = *(const uint4*)&m_b[((size_t)arow << 6) + s * 16 + kg * 4];
      s16x8 A = *(s16x8*)&av;
#pragma unroll
      for (int c = 0; c < 8; ++c) {
        int f = (c * 4 + s) * 64 + lane;
        s16x8 Bh = *(s16x8*)&W[f * 4];
        s16x8 Bl = *(s16x8*)&W[8192 + f * 4];
        acc[c] = __builtin_amdgcn_mfma_f32_16x16x32_bf16(A, Bh, acc[c], 0, 0, 0);
        acc[c] = __builtin_amdgcn_mfma_f32_16x16x32_bf16(A, Bl, acc[c], 0, 0, 0);
      }
    }
    int orow = rbase + kg * 4;
#pragma unroll
    for (int c = 0; c < 8; ++c) {
#pragma unroll
      for (int r = 0; r < 4; ++r) {
        if (orow + r < e0) pacc[c] += fmaxf(acc[c][r] + bb[c], 0.f);
      }
    }
  }
#pragma unroll
  for (int c = 0; c < 8; ++c) pool[wave * 4 + kg][c * 16 + col] = pacc[c];
  __syncthreads();
  int j = threadIdx.x;
  if (j < HD) {
    float a = 0.f;
#pragma unroll
    for (int r = 0; r < 16; ++r) a += pool[r][j];
    float cg = (float)(e0 - s0);
    cg = cg < 1.f ? 1.f : cg;
    ps[j] = a / cg;
  }
  __syncthreads();
  if (j < HD) {
    float a = fc1b[j];
#pragma unroll 4
    for (int k = 0; k < HD; ++k) a = fmaf(ps[k], fc1W[k * HD + j], a);
    rsh[j] = fmaxf(a, 0.f) * fc2W[j];
  }
  __syncthreads();
  for (int off = 64; off > 0; off >>= 1) {
    if (j < off) rsh[j] += rsh[j + off];
    __syncthreads();
  }
  if (j == 0) out[g] = rsh[0] + fc2b[0];
}

extern "C" void kernel_launch(void* const* d_in, const int* in_sizes, int n_in,
                              void* d_out, int out_size, void* d_ws, size_t ws_size,
                              hipStream_t stream) {
  const float* x    = (const float*)d_in[0];
  const int* esrc   = (const int*)d_in[1];
  const int* edst   = (const int*)d_in[2];
  const int* bids   = (const int*)d_in[3];
  const float* W1   = (const float*)d_in[5];
  const float* b1   = (const float*)d_in[6];
  const float* W2   = (const float*)d_in[7];
  const float* b2   = (const float*)d_in[8];
  const float* fc1W = (const float*)d_in[9];
  const float* fc1b = (const float*)d_in[10];
  const float* fc2W = (const float*)d_in[11];
  const float* fc2b = (const float*)d_in[12];
  float* out = (float*)d_out;

  const int N = in_sizes[0] / 2;
  const int E = in_sizes[1];
  const int G = out_size;

  const int NB = idiv(N, BNODES);       // buckets (391 for N=100K)
  const int M = NB * BINBLK;            // count-matrix size (~100K)
  const int chunk = idiv(E, BINBLK);

  char* w = (char*)d_ws;
  size_t o = 0;
  auto take = [&](size_t b) -> char* {
    char* p = w + o;
    o = (o + b + 255) & ~(size_t)255;
    return p;
  };
  int*      cntm      = (int*)     take((size_t)M * 4);
  int*      scanM     = (int*)     take((size_t)M * 4);
  int*      part      = (int*)     take(4096);
  unsigned* recs      = (unsigned*)take((size_t)E * 4);
  unsigned* ssrc16    = (unsigned*)take((size_t)(E + N + 256) * 4);
  int*      cnt       = (int*)     take((size_t)N * 4);
  int*      row_start = (int*)     take((size_t)N * 4);
  float*    dinv      = (float*)   take((size_t)N * 4);
  float*    xs        = (float*)   take((size_t)N * 8);
  float*    td        = (float*)   take((size_t)(N + 1) * 16);  // +sentinel row
  int*      gstart    = (int*)     take((size_t)(G + 1) * 4);
  unsigned* m_b       = (unsigned*)take((size_t)N * 64 * 4);    // bf16-packed m
  unsigned* w2f       = (unsigned*)take(16384 * 4);             // frag-linear W2 hi+lo

  int nbM = idiv(M, 1024);
  k_w2t_bincount<<<8 + BINBLK, 256, 0, stream>>>(W2, w2f, (float4*)td, edst,
                                                 cntm, E, NB, chunk, N);
  k_scan1<<<nbM, 256, 0, stream>>>(cntm, part, M);
  k_scan2<<<1, 1024, 0, stream>>>(part, nbM);
  k_scan3<<<nbM, 256, 0, stream>>>(cntm, part, scanM, M);
  k_binscatter<<<BINBLK, 256, 0, stream>>>(esrc, edst, scanM, recs, E, NB, chunk);
  k_bucketsort<<<NB, 256, 0, stream>>>(recs, scanM, x, bids, ssrc16, row_start,
                                       cnt, dinv, (float2*)xs, gstart, NB, N, G, E);
  k_aggx2<<<idiv(N, 256), 256, 0, stream>>>(row_start, cnt, ssrc16, (const float2*)xs,
                                            dinv, (float4*)td, N);
  int waves = idiv(N, PER);
  k_aggh<<<idiv(waves, 4), 256, 0, stream>>>(row_start, cnt, ssrc16, (const float4*)td,
                                             W1, b1, m_b, N);
  k_t2pool<<<G, 256, 0, stream>>>(m_b, w2f, b2, gstart, fc1W, fc1b, fc2W, fc2b, out, N, G);
}